// Round 1
// 196.492 us; speedup vs baseline: 1.0001x; 1.0001x over previous
//
#include <hip/hip_runtime.h>
#include <hip/hip_bf16.h>

// EdgeDecoder: out[e] = relu(concat(zu[row[e]], zr[col[e]]) @ W1 + b1) @ W2 + b2
// R4 strategy (polish of R3 two-pass):
//   prep_w1: one-time swizzle of W1 -> bf16 B-fragment layout in d_ws (64 KB).
//   proj_nodes: blocks split by node type (user blocks stage only W1[:128],
//     recipe blocks only W1[128:]) -> 32 KB LDS -> 4 blocks/CU (was 2 at 64 KB),
//     staging is a coalesced uint4 copy instead of per-block fp32->bf16 VALU
//     conversion. One 32-row tile per wave, grid exactly sized.
//   edge_pass: MLP experiment — 4 edges per 16-lane group (16/wave/iter),
//     8 interleaved row gathers in flight + full index prefetch. Tests
//     latency-bound vs fabric-bound hypothesis for the 3.37 TB/s gather path.

#define HDIM 128

typedef __attribute__((ext_vector_type(8))) __bf16 bf16x8;
typedef __attribute__((ext_vector_type(16))) float f32x16;

static __device__ __forceinline__ unsigned short bf16_bits(float x) {
  return __builtin_bit_cast(unsigned short, static_cast<__bf16>(x));
}

static __device__ __forceinline__ float bf2f(unsigned short u) {
  return __builtin_bit_cast(float, ((unsigned int)u) << 16);
}

static __device__ __forceinline__ bf16x8 cvt8(float4 a, float4 b) {
  bf16x8 r;
  r[0] = static_cast<__bf16>(a.x);
  r[1] = static_cast<__bf16>(a.y);
  r[2] = static_cast<__bf16>(a.z);
  r[3] = static_cast<__bf16>(a.w);
  r[4] = static_cast<__bf16>(b.x);
  r[5] = static_cast<__bf16>(b.y);
  r[6] = static_cast<__bf16>(b.z);
  r[7] = static_cast<__bf16>(b.w);
  return r;
}

// ---------- pass 0: one-time W1 swizzle (fp32 -> bf16 B-fragment layout) ----
// Layout (same as R1-verified Bsw): Bsw[((kc*4+nt)*64+ln)*8+j] where
//   k = kc*16 + (ln>>5)*8 + j, n = nt*32 + (ln&31); kc 0..7 = W1[:128],
//   kc 8..15 = W1[128:].
__global__ void prep_w1(const float* __restrict__ W1,
                        unsigned short* __restrict__ W1bf) {
  const int tid = threadIdx.x;
#pragma unroll
  for (int it = 0; it < 8; ++it) {
    const int idx = (blockIdx.x << 11) + (it << 8) + tid;  // 0..32767
    const int k = idx >> 7;
    const int n = idx & 127;
    const int kc = k >> 4;
    const int q = (k >> 3) & 1;
    const int j = k & 7;
    const int nt = n >> 5;
    const int ln = (q << 5) | (n & 31);
    W1bf[((((kc << 2) + nt) << 6) | ln) * 8 + j] = bf16_bits(W1[idx]);
  }
}

// ---------- pass 1: node projections (dense MFMA GEMM, no gather) ----------
__global__ __launch_bounds__(256, 4) void proj_nodes(
    const float* __restrict__ zu, int NU, const float* __restrict__ zr, int NR,
    const float* __restrict__ W1, const unsigned short* __restrict__ W1bf,
    unsigned short* __restrict__ Hu, unsigned short* __restrict__ Hr,
    int ublocks) {
  __shared__ unsigned short Bsw[16384];  // 32 KB: only this block's W1 half
  const int tid = threadIdx.x;
  const bool isU = (int)blockIdx.x < ublocks;
  const int kc0 = isU ? 0 : 8;

  if (W1bf) {
    // coalesced 32 KB copy of the pre-swizzled half
    const uint4* s4 = (const uint4*)(W1bf + (kc0 << 11));
    uint4* d4 = (uint4*)Bsw;
#pragma unroll
    for (int i = 0; i < 8; ++i) d4[(i << 8) + tid] = s4[(i << 8) + tid];
  } else {
    // fallback: in-kernel conversion of this half only
    const int n = tid & 127;
    const int kh = tid >> 7;
    const int nt = n >> 5;
    const int nl = n & 31;
#pragma unroll 8
    for (int it = 0; it < 64; ++it) {
      const int kl = 2 * it + kh;  // 0..127 local k
      const float w = W1[(kc0 * 16 + kl) * HDIM + n];
      const int kc = kl >> 4;      // 0..7 local
      const int q = (kl >> 3) & 1;
      const int j = kl & 7;
      const int ln = (q << 5) | nl;
      Bsw[((((kc << 2) + nt) << 6) | ln) * 8 + j] = bf16_bits(w);
    }
  }
  __syncthreads();

  const int lane = tid & 63;
  const int wid = tid >> 6;
  const int m = lane & 31;
  const int half = lane >> 5;
  const int koff = half * 8;

  const int tl = (isU ? (int)blockIdx.x : (int)blockIdx.x - ublocks) * 4 + wid;
  const int ntype = isU ? ((NU + 31) >> 5) : ((NR + 31) >> 5);
  if (tl >= ntype) return;  // no barriers after this point

  const int base = tl << 5;
  const int nmax = isU ? NU : NR;
  int node = base + m;
  if (node >= nmax) node = nmax - 1;  // clamped read for tail tile
  const float* src = (isU ? zu : zr) + (size_t)node * HDIM + koff;

  f32x16 acc[4];
#pragma unroll
  for (int nt = 0; nt < 4; ++nt) acc[nt] = (f32x16)0.0f;

#pragma unroll
  for (int kcl = 0; kcl < 8; ++kcl) {
    const float4* sa = (const float4*)(src + kcl * 16);
    const bf16x8 a = cvt8(sa[0], sa[1]);
#pragma unroll
    for (int nt = 0; nt < 4; ++nt) {
      const uint4* bp =
          (const uint4*)(Bsw + ((((kcl << 2) + nt) << 6) | lane) * 8);
      const bf16x8 bfr = __builtin_bit_cast(bf16x8, *bp);
      acc[nt] = __builtin_amdgcn_mfma_f32_32x32x16_bf16(a, bfr, acc[nt], 0, 0, 0);
    }
  }

  unsigned short* H = isU ? Hu : Hr;
#pragma unroll
  for (int nt = 0; nt < 4; ++nt) {
#pragma unroll
    for (int r = 0; r < 16; ++r) {
      const int row = (r & 3) + ((r >> 2) << 3) + (half << 2);
      const int nrow = base + row;
      if (nrow < nmax)
        H[(size_t)nrow * HDIM + (nt << 5) + m] = bf16_bits(acc[nt][r]);
    }
  }
}

// ---------- pass 2: gather + relu + dot(W2) ---------------------------------
static __device__ __forceinline__ float dot8(uint4 a, uint4 b,
                                             const float* b1c,
                                             const float* w2c) {
  const unsigned short* pa = (const unsigned short*)&a;
  const unsigned short* pb = (const unsigned short*)&b;
  float s = 0.f;
#pragma unroll
  for (int j = 0; j < 8; ++j) {
    const float h = bf2f(pa[j]) + bf2f(pb[j]) + b1c[j];
    s = fmaf(fmaxf(h, 0.f), w2c[j], s);
  }
  return s;
}

__global__ __launch_bounds__(256, 4) void edge_pass(
    const unsigned short* __restrict__ Hu, const unsigned short* __restrict__ Hr,
    const int* __restrict__ eidx, const float* __restrict__ b1,
    const float* __restrict__ W2, const float* __restrict__ b2,
    float* __restrict__ out, int E) {
  const int tid = threadIdx.x;
  const int lane = tid & 63;
  const int c = lane & 15;   // 16 B chunk within the 256 B row
  const int g = lane >> 4;   // edge-group within wave (4 groups)
  const int wid = blockIdx.x * 4 + (tid >> 6);
  const int stride = gridDim.x * 4 * 16;  // 16 edges per wave per iteration

  float b1c[8], w2c[8];
#pragma unroll
  for (int j = 0; j < 8; ++j) {
    b1c[j] = b1[c * 8 + j];
    w2c[j] = W2[c * 8 + j];
  }
  const float b2v = b2[0];
  const int co = c * 8;

  int e = wid * 16 + g * 4;  // wave covers 16 consecutive edges (E % 16 == 0)
  if (e >= E) return;
  int iu0 = eidx[e],     ir0 = eidx[E + e];
  int iu1 = eidx[e + 1], ir1 = eidx[E + e + 1];
  int iu2 = eidx[e + 2], ir2 = eidx[E + e + 2];
  int iu3 = eidx[e + 3], ir3 = eidx[E + e + 3];

  while (true) {
    const int en = e + stride;
    const bool more = en < E;
    const int ep = more ? en : e;

    // 8 gather loads in flight, interleaved so the first consumer waits
    // with maximum outstanding misses behind it
    const uint4 au0 = *(const uint4*)(Hu + (size_t)iu0 * HDIM + co);
    const uint4 ar0 = *(const uint4*)(Hr + (size_t)ir0 * HDIM + co);
    const uint4 au1 = *(const uint4*)(Hu + (size_t)iu1 * HDIM + co);
    const uint4 ar1 = *(const uint4*)(Hr + (size_t)ir1 * HDIM + co);
    const uint4 au2 = *(const uint4*)(Hu + (size_t)iu2 * HDIM + co);
    const uint4 ar2 = *(const uint4*)(Hr + (size_t)ir2 * HDIM + co);
    const uint4 au3 = *(const uint4*)(Hu + (size_t)iu3 * HDIM + co);
    const uint4 ar3 = *(const uint4*)(Hr + (size_t)ir3 * HDIM + co);

    const int niu0 = eidx[ep],     nir0 = eidx[E + ep];
    const int niu1 = eidx[ep + 1], nir1 = eidx[E + ep + 1];
    const int niu2 = eidx[ep + 2], nir2 = eidx[E + ep + 2];
    const int niu3 = eidx[ep + 3], nir3 = eidx[E + ep + 3];

    float s0 = dot8(au0, ar0, b1c, w2c);
    float s1 = dot8(au1, ar1, b1c, w2c);
    float s2 = dot8(au2, ar2, b1c, w2c);
    float s3 = dot8(au3, ar3, b1c, w2c);
#pragma unroll
    for (int st = 1; st <= 8; st <<= 1) {
      s0 += __shfl_xor(s0, st);
      s1 += __shfl_xor(s1, st);
      s2 += __shfl_xor(s2, st);
      s3 += __shfl_xor(s3, st);
    }
    if (c == 0) {
      out[e]     = s0 + b2v;
      out[e + 1] = s1 + b2v;
      out[e + 2] = s2 + b2v;
      out[e + 3] = s3 + b2v;
    }
    if (!more) break;
    e = en;
    iu0 = niu0; ir0 = nir0; iu1 = niu1; ir1 = nir1;
    iu2 = niu2; ir2 = nir2; iu3 = niu3; ir3 = nir3;
  }
}

// ---------- fallback (R1 kernel, fp32 gathers, no workspace) ---------------
__global__ __launch_bounds__(256, 2) void edge_decoder_mfma(
    const float* __restrict__ zu, const float* __restrict__ zr,
    const int* __restrict__ eidx, const float* __restrict__ W1,
    const float* __restrict__ b1, const float* __restrict__ W2,
    const float* __restrict__ b2, float* __restrict__ out, int E) {
  __shared__ unsigned short Bsw[32768];
  const int tid = threadIdx.x;
  {
    const int n = tid & 127;
    const int kh = tid >> 7;
    const int nt = n >> 5;
    const int nl = n & 31;
#pragma unroll 8
    for (int it = 0; it < 128; ++it) {
      const int k = 2 * it + kh;
      const float w = W1[k * HDIM + n];
      const int kc = k >> 4;
      const int q = (k >> 3) & 1;
      const int j = k & 7;
      const int ln = (q << 5) | nl;
      Bsw[((((kc << 2) + nt) << 6) | ln) * 8 + j] = bf16_bits(w);
    }
  }
  __syncthreads();

  const int lane = tid & 63;
  const int wid = tid >> 6;
  const int m = lane & 31;
  const int half = lane >> 5;
  const int nsweep = E >> 6;
  const int wstride = gridDim.x * 4;

  float b1v[4], w2v[4];
#pragma unroll
  for (int nt = 0; nt < 4; ++nt) {
    b1v[nt] = b1[nt * 32 + m];
    w2v[nt] = W2[nt * 32 + m];
  }
  const float b2v = b2[0];
  const int koff = half * 8;

  for (int s = blockIdx.x * 4 + wid; s < nsweep; s += wstride) {
    const int e0 = s << 6;
    const int eA = e0 + m;
    const int eB = e0 + 32 + m;
    const float* puA = zu + (size_t)eidx[eA] * HDIM;
    const float* prA = zr + (size_t)eidx[E + eA] * HDIM;
    const float* puB = zu + (size_t)eidx[eB] * HDIM;
    const float* prB = zr + (size_t)eidx[E + eB] * HDIM;

    f32x16 acc[2][4];
#pragma unroll
    for (int mt = 0; mt < 2; ++mt)
#pragma unroll
      for (int nt = 0; nt < 4; ++nt) acc[mt][nt] = (f32x16)0.0f;

#pragma unroll
    for (int kc = 0; kc < 16; ++kc) {
      const float* srcA = (kc < 8) ? (puA + kc * 16 + koff) : (prA + (kc - 8) * 16 + koff);
      const float* srcB = (kc < 8) ? (puB + kc * 16 + koff) : (prB + (kc - 8) * 16 + koff);
      const float4* sa = (const float4*)srcA;
      const float4* sb = (const float4*)srcB;
      const bf16x8 a0 = cvt8(sa[0], sa[1]);
      const bf16x8 a1 = cvt8(sb[0], sb[1]);
#pragma unroll
      for (int nt = 0; nt < 4; ++nt) {
        const uint4* bp = (const uint4*)(Bsw + ((((kc << 2) + nt) << 6) | lane) * 8);
        const bf16x8 bfr = __builtin_bit_cast(bf16x8, *bp);
        acc[0][nt] = __builtin_amdgcn_mfma_f32_32x32x16_bf16(a0, bfr, acc[0][nt], 0, 0, 0);
        acc[1][nt] = __builtin_amdgcn_mfma_f32_32x32x16_bf16(a1, bfr, acc[1][nt], 0, 0, 0);
      }
    }

    float p0[16], p1[16];
#pragma unroll
    for (int r = 0; r < 16; ++r) { p0[r] = 0.f; p1[r] = 0.f; }
#pragma unroll
    for (int nt = 0; nt < 4; ++nt) {
#pragma unroll
      for (int r = 0; r < 16; ++r) {
        float h0 = fmaxf(acc[0][nt][r] + b1v[nt], 0.f);
        float h1 = fmaxf(acc[1][nt][r] + b1v[nt], 0.f);
        p0[r] = fmaf(h0, w2v[nt], p0[r]);
        p1[r] = fmaf(h1, w2v[nt], p1[r]);
      }
    }
#pragma unroll
    for (int st = 1; st <= 16; st <<= 1) {
#pragma unroll
      for (int r = 0; r < 16; ++r) {
        p0[r] += __shfl_xor(p0[r], st);
        p1[r] += __shfl_xor(p1[r], st);
      }
    }
    const int sel = lane & 15;
    const int mtw = (lane >> 4) & 1;
    float val = 0.f;
#pragma unroll
    for (int r = 0; r < 16; ++r) {
      const float cand = mtw ? p1[r] : p0[r];
      val = (sel == r) ? cand : val;
    }
    const int mrow = (sel & 3) + ((sel >> 2) << 3) + (half << 2);
    out[e0 + (mtw << 5) + mrow] = val + b2v;
  }
}

extern "C" void kernel_launch(void* const* d_in, const int* in_sizes, int n_in,
                              void* d_out, int out_size, void* d_ws,
                              size_t ws_size, hipStream_t stream) {
  const float* zu = (const float*)d_in[0];
  const float* zr = (const float*)d_in[1];
  const int* eidx = (const int*)d_in[2];
  const float* W1 = (const float*)d_in[3];
  const float* b1 = (const float*)d_in[4];
  const float* W2 = (const float*)d_in[5];
  const float* b2 = (const float*)d_in[6];
  float* out = (float*)d_out;
  const int nu = in_sizes[0];     // N_USER * 128
  const int nr = in_sizes[1];     // N_RECIPE * 128
  const int E = in_sizes[2] / 2;  // 1,000,000
  const int NU = nu / HDIM, NR = nr / HDIM;

  const size_t needH = (size_t)(nu + nr) * sizeof(unsigned short);
  const size_t needW = 32768 * sizeof(unsigned short);

  if (ws_size >= needH) {
    unsigned short* Hu = (unsigned short*)d_ws;
    unsigned short* Hr = Hu + (size_t)nu;
    unsigned short* W1bf = nullptr;
    if (ws_size >= needH + needW) {
      W1bf = Hr + (size_t)nr;
      hipLaunchKernelGGL(prep_w1, dim3(16), dim3(256), 0, stream, W1, W1bf);
    }
    const int utiles = (NU + 31) >> 5;
    const int rtiles = (NR + 31) >> 5;
    const int ub = (utiles + 3) >> 2;
    const int rb = (rtiles + 3) >> 2;
    hipLaunchKernelGGL(proj_nodes, dim3(ub + rb), dim3(256), 0, stream,
                       zu, NU, zr, NR, W1, W1bf, Hu, Hr, ub);
    hipLaunchKernelGGL(edge_pass, dim3(2048), dim3(256), 0, stream,
                       Hu, Hr, eidx, b1, W2, b2, out, E);
  } else {
    hipLaunchKernelGGL(edge_decoder_mfma, dim3(512), dim3(256), 0, stream,
                       zu, zr, eidx, W1, b1, W2, b2, out, E);
  }
}

// Round 2
// 192.585 us; speedup vs baseline: 1.0204x; 1.0203x over previous
//
#include <hip/hip_runtime.h>
#include <hip/hip_bf16.h>

// EdgeDecoder: out[e] = relu(concat(zu[row[e]], zr[col[e]]) @ W1 + b1) @ W2 + b2
// R5 strategy:
//   prep: W1 swizzle (blocks 0-15) + per-block row-index max scan (all 64
//     blocks, plain stores into maxarr[64] -> no zeroing/stale-state hazard).
//   proj_nodes: user tiles with base > max(row) are skipped (conservative,
//     data-adaptive -> for this data only users [0,50k) are projected, -33%
//     tiles, -38 MB traffic). 32 KB LDS, 4 blocks/CU, exact grid.
//   edge_pass: 2x oversubscribed grid (4096 blocks) to test TLP-limited vs
//     fabric-ceiling hypothesis for the 3.4 TB/s random-gather rate.

#define HDIM 128

typedef __attribute__((ext_vector_type(8))) __bf16 bf16x8;
typedef __attribute__((ext_vector_type(16))) float f32x16;

static __device__ __forceinline__ unsigned short bf16_bits(float x) {
  return __builtin_bit_cast(unsigned short, static_cast<__bf16>(x));
}

static __device__ __forceinline__ float bf2f(unsigned short u) {
  return __builtin_bit_cast(float, ((unsigned int)u) << 16);
}

static __device__ __forceinline__ bf16x8 cvt8(float4 a, float4 b) {
  bf16x8 r;
  r[0] = static_cast<__bf16>(a.x);
  r[1] = static_cast<__bf16>(a.y);
  r[2] = static_cast<__bf16>(a.z);
  r[3] = static_cast<__bf16>(a.w);
  r[4] = static_cast<__bf16>(b.x);
  r[5] = static_cast<__bf16>(b.y);
  r[6] = static_cast<__bf16>(b.z);
  r[7] = static_cast<__bf16>(b.w);
  return r;
}

// ---------- pass 0: W1 swizzle + row-max scan -------------------------------
// W1bf layout (R1-verified Bsw): Bsw[((kc*4+nt)*64+ln)*8+j] where
//   k = kc*16 + (ln>>5)*8 + j, n = nt*32 + (ln&31); kc 0..7 = W1[:128],
//   kc 8..15 = W1[128:].
// maxarr[b] = max over this block's slice of eidx[0..E) (user row indices).
//   Plain stores, fully overwritten every launch -> first-run/poison safe.
__global__ __launch_bounds__(256) void prep(const float* __restrict__ W1,
                                            unsigned short* __restrict__ W1bf,
                                            const int* __restrict__ eidx, int E,
                                            int* __restrict__ maxarr) {
  const int tid = threadIdx.x;
  const int b = blockIdx.x;
  if (b < 16 && W1bf) {
#pragma unroll
    for (int it = 0; it < 8; ++it) {
      const int idx = (b << 11) + (it << 8) + tid;  // 0..32767
      const int k = idx >> 7;
      const int n = idx & 127;
      const int kc = k >> 4;
      const int q = (k >> 3) & 1;
      const int j = k & 7;
      const int nt = n >> 5;
      const int ln = (q << 5) | (n & 31);
      W1bf[((((kc << 2) + nt) << 6) | ln) * 8 + j] = bf16_bits(W1[idx]);
    }
  }
  // per-block max of user row indices
  int local = -1;
  for (int i = b * 256 + tid; i < E; i += 64 * 256)
    local = max(local, eidx[i]);
#pragma unroll
  for (int st = 1; st <= 32; st <<= 1)
    local = max(local, __shfl_xor(local, st));
  __shared__ int wmax[4];
  if ((tid & 63) == 0) wmax[tid >> 6] = local;
  __syncthreads();
  if (tid == 0) {
    int m = max(max(wmax[0], wmax[1]), max(wmax[2], wmax[3]));
    maxarr[b] = m;
  }
}

// ---------- pass 1: node projections (dense MFMA GEMM, no gather) ----------
__global__ __launch_bounds__(256, 4) void proj_nodes(
    const float* __restrict__ zu, int NU, const float* __restrict__ zr, int NR,
    const float* __restrict__ W1, const unsigned short* __restrict__ W1bf,
    const int* __restrict__ maxarr,
    unsigned short* __restrict__ Hu, unsigned short* __restrict__ Hr,
    int ublocks) {
  __shared__ unsigned short Bsw[16384];  // 32 KB: only this block's W1 half
  const int tid = threadIdx.x;
  const bool isU = (int)blockIdx.x < ublocks;
  const int kc0 = isU ? 0 : 8;

  if (W1bf) {
    // coalesced 32 KB copy of the pre-swizzled half
    const uint4* s4 = (const uint4*)(W1bf + (kc0 << 11));
    uint4* d4 = (uint4*)Bsw;
#pragma unroll
    for (int i = 0; i < 8; ++i) d4[(i << 8) + tid] = s4[(i << 8) + tid];
  } else {
    // fallback: in-kernel conversion of this half only
    const int n = tid & 127;
    const int kh = tid >> 7;
    const int nt = n >> 5;
    const int nl = n & 31;
#pragma unroll 8
    for (int it = 0; it < 64; ++it) {
      const int kl = 2 * it + kh;  // 0..127 local k
      const float w = W1[(kc0 * 16 + kl) * HDIM + n];
      const int kc = kl >> 4;      // 0..7 local
      const int q = (kl >> 3) & 1;
      const int j = kl & 7;
      const int ln = (q << 5) | nl;
      Bsw[((((kc << 2) + nt) << 6) | ln) * 8 + j] = bf16_bits(w);
    }
  }
  __syncthreads();

  const int lane = tid & 63;
  const int wid = tid >> 6;
  const int m = lane & 31;
  const int half = lane >> 5;
  const int koff = half * 8;

  const int tl = (isU ? (int)blockIdx.x : (int)blockIdx.x - ublocks) * 4 + wid;
  const int ntype = isU ? ((NU + 31) >> 5) : ((NR + 31) >> 5);
  if (tl >= ntype) return;  // no barriers after this point

  const int base = tl << 5;

  // skip user tiles no edge references (maxarr holds per-prep-block maxima;
  // reduce 64 slots across the wave -> umax >= true max row index)
  if (isU && maxarr) {
    int v = maxarr[lane];
#pragma unroll
    for (int st = 1; st <= 32; st <<= 1) v = max(v, __shfl_xor(v, st));
    if (base > v) return;  // conservative: never skips a referenced tile
  }

  const int nmax = isU ? NU : NR;
  int node = base + m;
  if (node >= nmax) node = nmax - 1;  // clamped read for tail tile
  const float* src = (isU ? zu : zr) + (size_t)node * HDIM + koff;

  f32x16 acc[4];
#pragma unroll
  for (int nt = 0; nt < 4; ++nt) acc[nt] = (f32x16)0.0f;

#pragma unroll
  for (int kcl = 0; kcl < 8; ++kcl) {
    const float4* sa = (const float4*)(src + kcl * 16);
    const bf16x8 a = cvt8(sa[0], sa[1]);
#pragma unroll
    for (int nt = 0; nt < 4; ++nt) {
      const uint4* bp =
          (const uint4*)(Bsw + ((((kcl << 2) + nt) << 6) | lane) * 8);
      const bf16x8 bfr = __builtin_bit_cast(bf16x8, *bp);
      acc[nt] = __builtin_amdgcn_mfma_f32_32x32x16_bf16(a, bfr, acc[nt], 0, 0, 0);
    }
  }

  unsigned short* H = isU ? Hu : Hr;
#pragma unroll
  for (int nt = 0; nt < 4; ++nt) {
#pragma unroll
    for (int r = 0; r < 16; ++r) {
      const int row = (r & 3) + ((r >> 2) << 3) + (half << 2);
      const int nrow = base + row;
      if (nrow < nmax)
        H[(size_t)nrow * HDIM + (nt << 5) + m] = bf16_bits(acc[nt][r]);
    }
  }
}

// ---------- pass 2: gather + relu + dot(W2) ---------------------------------
static __device__ __forceinline__ float dot8(uint4 a, uint4 b,
                                             const float* b1c,
                                             const float* w2c) {
  const unsigned short* pa = (const unsigned short*)&a;
  const unsigned short* pb = (const unsigned short*)&b;
  float s = 0.f;
#pragma unroll
  for (int j = 0; j < 8; ++j) {
    const float h = bf2f(pa[j]) + bf2f(pb[j]) + b1c[j];
    s = fmaf(fmaxf(h, 0.f), w2c[j], s);
  }
  return s;
}

__global__ __launch_bounds__(256, 4) void edge_pass(
    const unsigned short* __restrict__ Hu, const unsigned short* __restrict__ Hr,
    const int* __restrict__ eidx, const float* __restrict__ b1,
    const float* __restrict__ W2, const float* __restrict__ b2,
    float* __restrict__ out, int E) {
  const int tid = threadIdx.x;
  const int lane = tid & 63;
  const int c = lane & 15;   // 16 B chunk within the 256 B row
  const int g = lane >> 4;   // edge-group within wave (4 groups)
  const int wid = blockIdx.x * 4 + (tid >> 6);
  const int stride = gridDim.x * 4 * 16;  // 16 edges per wave per iteration

  float b1c[8], w2c[8];
#pragma unroll
  for (int j = 0; j < 8; ++j) {
    b1c[j] = b1[c * 8 + j];
    w2c[j] = W2[c * 8 + j];
  }
  const float b2v = b2[0];
  const int co = c * 8;

  int e = wid * 16 + g * 4;  // wave covers 16 consecutive edges (E % 16 == 0)
  if (e >= E) return;
  int iu0 = eidx[e],     ir0 = eidx[E + e];
  int iu1 = eidx[e + 1], ir1 = eidx[E + e + 1];
  int iu2 = eidx[e + 2], ir2 = eidx[E + e + 2];
  int iu3 = eidx[e + 3], ir3 = eidx[E + e + 3];

  while (true) {
    const int en = e + stride;
    const bool more = en < E;
    const int ep = more ? en : e;

    // 8 gather loads in flight, interleaved so the first consumer waits
    // with maximum outstanding misses behind it
    const uint4 au0 = *(const uint4*)(Hu + (size_t)iu0 * HDIM + co);
    const uint4 ar0 = *(const uint4*)(Hr + (size_t)ir0 * HDIM + co);
    const uint4 au1 = *(const uint4*)(Hu + (size_t)iu1 * HDIM + co);
    const uint4 ar1 = *(const uint4*)(Hr + (size_t)ir1 * HDIM + co);
    const uint4 au2 = *(const uint4*)(Hu + (size_t)iu2 * HDIM + co);
    const uint4 ar2 = *(const uint4*)(Hr + (size_t)ir2 * HDIM + co);
    const uint4 au3 = *(const uint4*)(Hu + (size_t)iu3 * HDIM + co);
    const uint4 ar3 = *(const uint4*)(Hr + (size_t)ir3 * HDIM + co);

    const int niu0 = eidx[ep],     nir0 = eidx[E + ep];
    const int niu1 = eidx[ep + 1], nir1 = eidx[E + ep + 1];
    const int niu2 = eidx[ep + 2], nir2 = eidx[E + ep + 2];
    const int niu3 = eidx[ep + 3], nir3 = eidx[E + ep + 3];

    float s0 = dot8(au0, ar0, b1c, w2c);
    float s1 = dot8(au1, ar1, b1c, w2c);
    float s2 = dot8(au2, ar2, b1c, w2c);
    float s3 = dot8(au3, ar3, b1c, w2c);
#pragma unroll
    for (int st = 1; st <= 8; st <<= 1) {
      s0 += __shfl_xor(s0, st);
      s1 += __shfl_xor(s1, st);
      s2 += __shfl_xor(s2, st);
      s3 += __shfl_xor(s3, st);
    }
    if (c == 0) {
      out[e]     = s0 + b2v;
      out[e + 1] = s1 + b2v;
      out[e + 2] = s2 + b2v;
      out[e + 3] = s3 + b2v;
    }
    if (!more) break;
    e = en;
    iu0 = niu0; ir0 = nir0; iu1 = niu1; ir1 = nir1;
    iu2 = niu2; ir2 = nir2; iu3 = niu3; ir3 = nir3;
  }
}

// ---------- fallback (R1 kernel, fp32 gathers, no workspace) ---------------
__global__ __launch_bounds__(256, 2) void edge_decoder_mfma(
    const float* __restrict__ zu, const float* __restrict__ zr,
    const int* __restrict__ eidx, const float* __restrict__ W1,
    const float* __restrict__ b1, const float* __restrict__ W2,
    const float* __restrict__ b2, float* __restrict__ out, int E) {
  __shared__ unsigned short Bsw[32768];
  const int tid = threadIdx.x;
  {
    const int n = tid & 127;
    const int kh = tid >> 7;
    const int nt = n >> 5;
    const int nl = n & 31;
#pragma unroll 8
    for (int it = 0; it < 128; ++it) {
      const int k = 2 * it + kh;
      const float w = W1[k * HDIM + n];
      const int kc = k >> 4;
      const int q = (k >> 3) & 1;
      const int j = k & 7;
      const int ln = (q << 5) | nl;
      Bsw[((((kc << 2) + nt) << 6) | ln) * 8 + j] = bf16_bits(w);
    }
  }
  __syncthreads();

  const int lane = tid & 63;
  const int wid = tid >> 6;
  const int m = lane & 31;
  const int half = lane >> 5;
  const int nsweep = E >> 6;
  const int wstride = gridDim.x * 4;

  float b1v[4], w2v[4];
#pragma unroll
  for (int nt = 0; nt < 4; ++nt) {
    b1v[nt] = b1[nt * 32 + m];
    w2v[nt] = W2[nt * 32 + m];
  }
  const float b2v = b2[0];
  const int koff = half * 8;

  for (int s = blockIdx.x * 4 + wid; s < nsweep; s += wstride) {
    const int e0 = s << 6;
    const int eA = e0 + m;
    const int eB = e0 + 32 + m;
    const float* puA = zu + (size_t)eidx[eA] * HDIM;
    const float* prA = zr + (size_t)eidx[E + eA] * HDIM;
    const float* puB = zu + (size_t)eidx[eB] * HDIM;
    const float* prB = zr + (size_t)eidx[E + eB] * HDIM;

    f32x16 acc[2][4];
#pragma unroll
    for (int mt = 0; mt < 2; ++mt)
#pragma unroll
      for (int nt = 0; nt < 4; ++nt) acc[mt][nt] = (f32x16)0.0f;

#pragma unroll
    for (int kc = 0; kc < 16; ++kc) {
      const float* srcA = (kc < 8) ? (puA + kc * 16 + koff) : (prA + (kc - 8) * 16 + koff);
      const float* srcB = (kc < 8) ? (puB + kc * 16 + koff) : (prB + (kc - 8) * 16 + koff);
      const float4* sa = (const float4*)srcA;
      const float4* sb = (const float4*)srcB;
      const bf16x8 a0 = cvt8(sa[0], sa[1]);
      const bf16x8 a1 = cvt8(sb[0], sb[1]);
#pragma unroll
      for (int nt = 0; nt < 4; ++nt) {
        const uint4* bp = (const uint4*)(Bsw + ((((kc << 2) + nt) << 6) | lane) * 8);
        const bf16x8 bfr = __builtin_bit_cast(bf16x8, *bp);
        acc[0][nt] = __builtin_amdgcn_mfma_f32_32x32x16_bf16(a0, bfr, acc[0][nt], 0, 0, 0);
        acc[1][nt] = __builtin_amdgcn_mfma_f32_32x32x16_bf16(a1, bfr, acc[1][nt], 0, 0, 0);
      }
    }

    float p0[16], p1[16];
#pragma unroll
    for (int r = 0; r < 16; ++r) { p0[r] = 0.f; p1[r] = 0.f; }
#pragma unroll
    for (int nt = 0; nt < 4; ++nt) {
#pragma unroll
      for (int r = 0; r < 16; ++r) {
        float h0 = fmaxf(acc[0][nt][r] + b1v[nt], 0.f);
        float h1 = fmaxf(acc[1][nt][r] + b1v[nt], 0.f);
        p0[r] = fmaf(h0, w2v[nt], p0[r]);
        p1[r] = fmaf(h1, w2v[nt], p1[r]);
      }
    }
#pragma unroll
    for (int st = 1; st <= 16; st <<= 1) {
#pragma unroll
      for (int r = 0; r < 16; ++r) {
        p0[r] += __shfl_xor(p0[r], st);
        p1[r] += __shfl_xor(p1[r], st);
      }
    }
    const int sel = lane & 15;
    const int mtw = (lane >> 4) & 1;
    float val = 0.f;
#pragma unroll
    for (int r = 0; r < 16; ++r) {
      const float cand = mtw ? p1[r] : p0[r];
      val = (sel == r) ? cand : val;
    }
    const int mrow = (sel & 3) + ((sel >> 2) << 3) + (half << 2);
    out[e0 + (mtw << 5) + mrow] = val + b2v;
  }
}

extern "C" void kernel_launch(void* const* d_in, const int* in_sizes, int n_in,
                              void* d_out, int out_size, void* d_ws,
                              size_t ws_size, hipStream_t stream) {
  const float* zu = (const float*)d_in[0];
  const float* zr = (const float*)d_in[1];
  const int* eidx = (const int*)d_in[2];
  const float* W1 = (const float*)d_in[3];
  const float* b1 = (const float*)d_in[4];
  const float* W2 = (const float*)d_in[5];
  const float* b2 = (const float*)d_in[6];
  float* out = (float*)d_out;
  const int nu = in_sizes[0];     // N_USER * 128
  const int nr = in_sizes[1];     // N_RECIPE * 128
  const int E = in_sizes[2] / 2;  // 1,000,000
  const int NU = nu / HDIM, NR = nr / HDIM;

  const size_t needH = (size_t)(nu + nr) * sizeof(unsigned short);
  const size_t needW = 32768 * sizeof(unsigned short);
  const size_t needM = 64 * sizeof(int);

  if (ws_size >= needH) {
    unsigned short* Hu = (unsigned short*)d_ws;
    unsigned short* Hr = Hu + (size_t)nu;
    unsigned short* W1bf = nullptr;
    int* maxarr = nullptr;
    if (ws_size >= needH + needW + needM) {
      W1bf = Hr + (size_t)nr;
      maxarr = (int*)(W1bf + 32768);
      hipLaunchKernelGGL(prep, dim3(64), dim3(256), 0, stream,
                         W1, W1bf, eidx, E, maxarr);
    }
    const int utiles = (NU + 31) >> 5;
    const int rtiles = (NR + 31) >> 5;
    const int ub = (utiles + 3) >> 2;
    const int rb = (rtiles + 3) >> 2;
    hipLaunchKernelGGL(proj_nodes, dim3(ub + rb), dim3(256), 0, stream,
                       zu, NU, zr, NR, W1, W1bf, maxarr, Hu, Hr, ub);
    hipLaunchKernelGGL(edge_pass, dim3(4096), dim3(256), 0, stream,
                       Hu, Hr, eidx, b1, W2, b2, out, E);
  } else {
    hipLaunchKernelGGL(edge_decoder_mfma, dim3(512), dim3(256), 0, stream,
                       zu, zr, eidx, W1, b1, W2, b2, out, E);
  }
}